// Round 6
// baseline (1980.594 us; speedup 1.0000x reference)
//
#include <hip/hip_runtime.h>
#include <math.h>

#define N_ENTS   50000
#define N_RELS   400        // 2*N_REL
#define D_IN0    100
#define DD       200
#define E_DIR    250000
#define E_TOT    500000
#define BATCH    512
#define NFILT    200
#define FLATK    39200
#define EPSV     1e-5f
#define NKEY     (2 * N_ENTS)   // (side, row) keys: in rows [0,50000), out rows [50000,100000)

// ---------------- workspace layout (float offsets) ----------------
#define WS_X1      ((size_t)0)
#define WS_X2      ((size_t)10000000)
#define WS_R1      ((size_t)20000000)
#define WS_R2      ((size_t)20080000)
#define WS_DINV_IN ((size_t)20160000)
#define WS_DINV_OUT ((size_t)20210000)
#define WS_STATS   ((size_t)20260000)   // 4096 floats
// stats sublayout
#define ST_L1_SUM   0
#define ST_L1_SQ    200
#define ST_L2_SUM   400
#define ST_L2_SQ    600
#define ST_BN0      800   // [0]=sum [1]=sq
#define ST_BN1_SUM  802
#define ST_BN1_SQ   1002
#define ST_BN2_SUM  1202
#define ST_BN2_SQ   1402
#define ST_S1       1602
#define ST_T1       1802
#define WS_IMGRAW  ((size_t)20264096)   // 512*400
#define WS_IMG     ((size_t)20468896)   // 512*400 (unused now)
#define WS_FCACC   ((size_t)20673696)   // 512*200
#define WS_HFIN    ((size_t)20776096)   // 512*200
#define WS_BIG     ((size_t)20878528)   // 30,000,000 floats (agg1/agg2/conv_raw)

// ---------------- dinv from histogram counts ----------------
__global__ void dinv_kernel(const int* __restrict__ cnt, float* dinv_in, float* dinv_out) {
    int i = blockIdx.x * blockDim.x + threadIdx.x;
    if (i >= N_ENTS) return;
    int a = cnt[i];
    dinv_in[i]  = (a > 0) ? rsqrtf((float)a) : 0.f;
    int b = cnt[N_ENTS + i];
    dinv_out[i] = (b > 0) ? rsqrtf((float)b) : 0.f;
}

// ---------------- CSR build: histogram -> scan -> fill ----------------
__global__ void hist_kernel(const int* __restrict__ ei, int* __restrict__ cnt) {
    int e = blockIdx.x * blockDim.x + threadIdx.x;
    if (e >= E_TOT) return;
    int key = ei[e] + ((e < E_DIR) ? 0 : N_ENTS);
    atomicAdd(&cnt[key], 1);
}

// single-block exclusive scan of cnt[NKEY] -> startp[NKEY+1]
__global__ __launch_bounds__(1024) void scan_kernel(const int* __restrict__ cnt,
                                                    int* __restrict__ startp) {
    __shared__ int part[1024];
    const int tid = threadIdx.x;
    const int per = (NKEY + 1023) / 1024;   // 98
    int b = tid * per;
    int e = b + per; if (e > NKEY) e = NKEY;
    if (b > NKEY) b = NKEY;
    int s = 0;
    for (int i = b; i < e; i++) s += cnt[i];
    part[tid] = s;
    __syncthreads();
    for (int off = 1; off < 1024; off <<= 1) {
        int v = (tid >= off) ? part[tid - off] : 0;
        __syncthreads();
        part[tid] += v;
        __syncthreads();
    }
    int run = (tid == 0) ? 0 : part[tid - 1];
    for (int i = b; i < e; i++) { startp[i] = run; run += cnt[i]; }
    if (e == NKEY) startp[NKEY] = run;
}

// fill sorted edge records (col, type, dinv_side[col], pad); advances startp[key] to END
__global__ void fill_kernel(const int* __restrict__ ei, const int* __restrict__ et,
                            const float* __restrict__ dinv_in, const float* __restrict__ dinv_out,
                            int* __restrict__ startp, int4* __restrict__ rec) {
    int e = blockIdx.x * blockDim.x + threadIdx.x;
    if (e >= E_TOT) return;
    bool in_side = e < E_DIR;
    int key = ei[e] + (in_side ? 0 : N_ENTS);
    int pos = atomicAdd(&startp[key], 1);
    int col = ei[E_TOT + e];
    float sc = in_side ? dinv_in[col] : dinv_out[col];
    rec[pos] = make_int4(col, et[e], __float_as_int(sc), 0);
}

// ---------------- segmented reduction: agg[row, side] = sum over edges ----------------
// one int4 load per edge (col, t, sc); 1-deep prefetch; zero atomics.
template<int DIN, int STRIDE>
__global__ void seg_kernel(const int* __restrict__ startp, const int* __restrict__ cnt,
                           const int4* __restrict__ rec,
                           const float* __restrict__ x, const float* __restrict__ r,
                           float* __restrict__ agg) {
    int key = blockIdx.x;
    int d = threadIdx.x;
    if (d >= DIN) return;
    int end = startp[key];
    int beg = end - cnt[key];
    bool in_side = key < N_ENTS;
    int row = in_side ? key : key - N_ENTS;
    float acc = 0.f;
    if (beg < end) {
        int4 rc = rec[beg];
        for (int p = beg; p + 1 < end; p++) {
            int4 nx = rec[p + 1];   // prefetch next record while current x/r loads resolve
            acc += x[(size_t)rc.x * DIN + d] * r[(size_t)rc.y * DIN + d] * __int_as_float(rc.z);
            rc = nx;
        }
        acc += x[(size_t)rc.x * DIN + d] * r[(size_t)rc.y * DIN + d] * __int_as_float(rc.z);
    }
    agg[(size_t)row * STRIDE + (in_side ? 0 : DIN) + d] = acc;
}

// ---------------- layer GEMM v5: BK=8 dbuf, split-B, fused loop-compose ----------------
// out[M=N_ENTS, N=200] = [scaled(agg[M, 2*DIN]) | x*loop_rel] @ [w_in; w_out; w_loop]
template<int DIN>
__launch_bounds__(256, 2)
__global__ void gemm_layer(const float* __restrict__ agg,
                           const float* __restrict__ x, const float* __restrict__ loop_rel,
                           const float* __restrict__ w_in, const float* __restrict__ w_out,
                           const float* __restrict__ w_loop,
                           const float* __restrict__ dinv_in, const float* __restrict__ dinv_out,
                           float* __restrict__ out) {
    const int K = 3 * DIN;
    __shared__ float As[2][8][132];   // [buf][k][m]
    __shared__ float Bs[2][8][132];   // [buf][k][n]
    const int m0 = blockIdx.x * 128;
    const int n0 = blockIdx.y * 128;
    const int tid = threadIdx.x;
    const int tx = tid & 15, ty = tid >> 4;
    const int am  = tid >> 1;          // A row 0..127
    const int akc = (tid & 1) * 4;     // A k-offset 0,4
    const int bk = tid >> 5;           // B k 0..7
    const int bn = (tid & 31) * 4;     // B n-offset 0..124

    const int gm = m0 + am;
    const bool mval = gm < N_ENTS;
    const float scin  = mval ? dinv_in[gm]  : 0.f;
    const float scout = mval ? dinv_out[gm] : 0.f;
    const float* arow = &agg[(size_t)gm * (2 * DIN)];
    const float* xrow = &x[(size_t)gm * DIN];
    const bool bnval = (n0 + bn + 3) < DD;

    auto loadA = [&](int k0) -> float4 {
        int kg = k0 + akc;
        float4 v = make_float4(0.f, 0.f, 0.f, 0.f);
        if (mval && kg < K) {
            if (kg < 2 * DIN) {
                v = *(const float4*)&arow[kg];
            } else {
                int kk = kg - 2 * DIN;
                float4 xv = *(const float4*)&xrow[kk];
                float4 lv = *(const float4*)&loop_rel[kk];
                v = make_float4(xv.x * lv.x, xv.y * lv.y, xv.z * lv.z, xv.w * lv.w);
            }
        }
        return v;
    };
    auto loadB = [&](int k0) -> float4 {
        int kg = k0 + bk;
        float4 v = make_float4(0.f, 0.f, 0.f, 0.f);
        if (kg < K && bnval) {
            const float* wsrc; int kk;
            if (kg < DIN)          { wsrc = w_in;   kk = kg; }
            else if (kg < 2 * DIN) { wsrc = w_out;  kk = kg - DIN; }
            else                   { wsrc = w_loop; kk = kg - 2 * DIN; }
            v = *(const float4*)&wsrc[(size_t)kk * DD + n0 + bn];
        }
        return v;
    };
    auto stageA = [&](int k0, float4 v, int buf) {
        int kg = k0 + akc;
        float s = (kg < DIN) ? scin : ((kg < 2 * DIN) ? scout : 1.0f);
        As[buf][akc + 0][am] = v.x * s;
        As[buf][akc + 1][am] = v.y * s;
        As[buf][akc + 2][am] = v.z * s;
        As[buf][akc + 3][am] = v.w * s;
    };
    auto stageB = [&](float4 v, int buf) {
        *(float4*)&Bs[buf][bk][bn] = v;
    };

    float acc[8][8] = {};

    stageA(0, loadA(0), 0);
    stageB(loadB(0), 0);
    __syncthreads();
    int cur = 0;

    for (int k0 = 0; k0 < K; k0 += 8) {
        const int nxt = k0 + 8;
        const bool have = nxt < K;
        float4 na = make_float4(0.f, 0.f, 0.f, 0.f), nb = na;
        if (have) { na = loadA(nxt); nb = loadB(nxt); }
#pragma unroll
        for (int k = 0; k < 8; k++) {
            float4 a0 = *(const float4*)&As[cur][k][ty * 8];
            float4 a1 = *(const float4*)&As[cur][k][ty * 8 + 4];
            float4 b0 = *(const float4*)&Bs[cur][k][tx * 4];
            float4 b1 = *(const float4*)&Bs[cur][k][64 + tx * 4];
            float av[8] = {a0.x, a0.y, a0.z, a0.w, a1.x, a1.y, a1.z, a1.w};
            float bv[8] = {b0.x, b0.y, b0.z, b0.w, b1.x, b1.y, b1.z, b1.w};
#pragma unroll
            for (int i = 0; i < 8; i++)
#pragma unroll
                for (int j = 0; j < 8; j++) acc[i][j] += av[i] * bv[j];
        }
        if (have) {
            stageA(nxt, na, cur ^ 1);
            stageB(nb, cur ^ 1);
            __syncthreads();
            cur ^= 1;
        }
    }

    const int nb0 = n0 + tx * 4;
    const int nb1 = n0 + 64 + tx * 4;
    const bool v0 = (nb0 + 3) < DD;
    const bool v1 = (nb1 + 3) < DD;
#pragma unroll
    for (int i = 0; i < 8; i++) {
        int m = m0 + ty * 8 + i;
        if (m < N_ENTS) {
            if (v0) *(float4*)&out[(size_t)m * DD + nb0] = make_float4(acc[i][0], acc[i][1], acc[i][2], acc[i][3]);
            if (v1) *(float4*)&out[(size_t)m * DD + nb1] = make_float4(acc[i][4], acc[i][5], acc[i][6], acc[i][7]);
        }
    }
}

// ---------------- per-feature stats: thread owns column f, private reg accumulation ----------------
__global__ void feat_stats_kernel(const float* __restrict__ x, int n_rows,
                                  float* __restrict__ sum, float* __restrict__ sq) {
    int f = threadIdx.x;            // 256 threads, active < 200
    if (f >= DD) return;
    int rows_per = (n_rows + gridDim.x - 1) / gridDim.x;
    int r0 = blockIdx.x * rows_per;
    int r1 = r0 + rows_per; if (r1 > n_rows) r1 = n_rows;
    float s = 0.f, q = 0.f;
    for (int rr = r0; rr < r1; rr++) {
        float v = x[(size_t)rr * DD + f];
        s += v; q += v * v;
    }
    atomicAdd(&sum[f], s);
    atomicAdd(&sq[f], q);
}

// ---------------- BN over nodes of y/3 + tanh, in place ----------------
__global__ void layer_apply_kernel(float* __restrict__ x,
                                   const float* __restrict__ sum, const float* __restrict__ sq,
                                   const float* __restrict__ g, const float* __restrict__ b) {
    int e = blockIdx.x * blockDim.x + threadIdx.x;
    if (e >= N_ENTS * DD) return;
    int f = e % DD;
    float mean = sum[f] * (1.0f / (3.0f * N_ENTS));
    float msq  = sq[f] * (1.0f / (9.0f * (float)N_ENTS));
    float var = msq - mean * mean;
    float v = (x[e] * (1.0f / 3.0f) - mean) * rsqrtf(var + EPSV) * g[f] + b[f];
    x[e] = tanhf(v);
}

// ---------------- relation transform: rout[400,200] = rprev[400,K] @ w_rel[K,200] ----------------
template<int KDIM>
__global__ void rel_kernel(const float* __restrict__ rprev, const float* __restrict__ w_rel,
                           float* __restrict__ rout) {
    int i = blockIdx.x;       // 0..399
    int j = threadIdx.x;      // 256, active < 200
    if (j >= DD) return;
    float acc = 0.f;
    for (int k = 0; k < KDIM; k++)
        acc += rprev[(size_t)i * KDIM + k] * w_rel[(size_t)k * DD + j];
    rout[(size_t)i * DD + j] = acc;
}

// ---------------- gather sub/rel embeddings into image + bn0 stats ----------------
__global__ void gather_kernel(const int* __restrict__ sub, const int* __restrict__ rel,
                              const float* __restrict__ x2, const float* __restrict__ r2,
                              float* __restrict__ imgraw, float* __restrict__ bn0acc) {
    int b = blockIdx.x;       // 512
    int t = threadIdx.x;      // 512
    float v = 0.f;
    if (t < 400) {
        int d = t >> 1;
        v = (t & 1) ? r2[(size_t)rel[b] * DD + d] : x2[(size_t)sub[b] * DD + d];
        imgraw[b * 400 + t] = v;
    }
    float sqv = v * v;
    for (int o = 32; o > 0; o >>= 1) {
        v   += __shfl_down(v, o, 64);
        sqv += __shfl_down(sqv, o, 64);
    }
    __shared__ float s1[8], s2l[8];
    int wid = t >> 6, lane = t & 63;
    if (lane == 0) { s1[wid] = v; s2l[wid] = sqv; }
    __syncthreads();
    if (t == 0) {
        float a = 0.f, c = 0.f;
        for (int w = 0; w < 8; w++) { a += s1[w]; c += s2l[w]; }
        atomicAdd(&bn0acc[0], a);
        atomicAdd(&bn0acc[1], c);
    }
}

// ---------------- conv 7x7 VALID with fused bn0: [512,1,20,20] -> [512,200,14,14] ----------------
__global__ void conv_kernel(const float* __restrict__ imgraw, const float* __restrict__ bn0acc,
                            const float* __restrict__ g0, const float* __restrict__ b0,
                            const float* __restrict__ conv_w, float* __restrict__ conv_raw) {
    __shared__ float simg[400];
    __shared__ float sw[9800];
    int b = blockIdx.x;
    int t = threadIdx.x;  // 256
    // bn0 coefficients (same expression order as the old bn0_apply_kernel)
    const float inv_n = 1.0f / (BATCH * 400);
    float m = bn0acc[0] * inv_n;
    float var = bn0acc[1] * inv_n - m * m;
    float rs = rsqrtf(var + EPSV);
    float g0v = g0[0], b0v = b0[0];
    for (int i = t; i < 400; i += 256)
        simg[i] = (imgraw[b * 400 + i] - m) * rs * g0v + b0v;
    for (int i = t; i < 9800; i += 256) sw[i] = conv_w[i];
    __syncthreads();
    for (int o = t; o < FLATK; o += 256) {
        int f = o / 196;
        int ij = o % 196;
        int i = ij / 14, j = ij % 14;
        const float* wp = &sw[f * 49];
        const float* ip = &simg[i * 20 + j];
        float acc = 0.f;
#pragma unroll
        for (int p = 0; p < 7; p++)
#pragma unroll
            for (int q = 0; q < 7; q++)
                acc += ip[p * 20 + q] * wp[p * 7 + q];
        conv_raw[(size_t)b * FLATK + o] = acc;
    }
}

// ---------------- bn1 stats: per-filter sum/sq over (b, i, j) ----------------
__global__ void bn1_stats_kernel(const float* __restrict__ conv_raw,
                                 float* __restrict__ sum, float* __restrict__ sq) {
    int blk = blockIdx.x;          // b*200 + f, 102400 blocks
    int f = blk % 200;
    size_t base = (size_t)blk * 196;
    int lane = threadIdx.x;        // 64
    float s = 0.f, q = 0.f;
    for (int i = lane; i < 196; i += 64) {
        float v = conv_raw[base + i];
        s += v; q += v * v;
    }
    for (int o = 32; o > 0; o >>= 1) {
        s += __shfl_down(s, o, 64);
        q += __shfl_down(q, o, 64);
    }
    if (lane == 0) { atomicAdd(&sum[f], s); atomicAdd(&sq[f], q); }
}

__global__ void bn1_coef_kernel(const float* __restrict__ sum, const float* __restrict__ sq,
                                const float* __restrict__ g1, const float* __restrict__ b1,
                                float* __restrict__ s1, float* __restrict__ t1) {
    int f = threadIdx.x;
    if (f >= 200) return;
    const float inv_n = 1.0f / (BATCH * 196);
    float m = sum[f] * inv_n;
    float var = sq[f] * inv_n - m * m;
    float s = g1[f] * rsqrtf(var + EPSV);
    s1[f] = s;
    t1[f] = b1[f] - m * s;
}

// ---------------- FC GEMM v2: M=64 x N=200(full) x BK=32, split-K Z=49 ----------------
__global__ void gemm_fc(const float* __restrict__ conv_raw, const float* __restrict__ fc_w,
                        const float* __restrict__ s1g, const float* __restrict__ t1g,
                        float* __restrict__ fc_acc) {
    __shared__ float As[32][68];
    __shared__ float Bs[32][256];
    __shared__ float Ss1[200], St1[200];
    const int m0   = blockIdx.x * 64;
    const int kbeg = blockIdx.y * 800;
    const int tid  = threadIdx.x;
    const int tx = tid & 63, ty = tid >> 6;
    const int ar  = tid >> 2;
    const int akc = (tid & 3) * 8;

    for (int i = tid; i < 200; i += 256) { Ss1[i] = s1g[i]; St1[i] = t1g[i]; }
    __syncthreads();

    float acc[16][4] = {};
    for (int k0 = 0; k0 < 800; k0 += 32) {
        {
            const float4* gp = (const float4*)&conv_raw[(size_t)(m0 + ar) * FLATK + kbeg + k0 + akc];
            float4 v0 = gp[0], v1 = gp[1];
            float tmp[8] = {v0.x, v0.y, v0.z, v0.w, v1.x, v1.y, v1.z, v1.w};
#pragma unroll
            for (int j = 0; j < 8; j++) {
                int kg = kbeg + k0 + akc + j;
                int f = kg / 196;
                As[akc + j][ar] = fmaxf(tmp[j] * Ss1[f] + St1[f], 0.f);
            }
        }
        {
            const float4* gp = (const float4*)&fc_w[(size_t)(kbeg + k0) * 200];
            for (int idx = tid; idx < 1600; idx += 256) {
                float4 v = gp[idx];
                int k = idx / 50, n4 = (idx % 50) * 4;
                *(float4*)&Bs[k][n4] = v;
            }
        }
        __syncthreads();
#pragma unroll 4
        for (int k = 0; k < 32; k++) {
            float4 a0 = *(const float4*)&As[k][ty * 16];
            float4 a1 = *(const float4*)&As[k][ty * 16 + 4];
            float4 a2 = *(const float4*)&As[k][ty * 16 + 8];
            float4 a3 = *(const float4*)&As[k][ty * 16 + 12];
            float av[16] = {a0.x, a0.y, a0.z, a0.w, a1.x, a1.y, a1.z, a1.w,
                            a2.x, a2.y, a2.z, a2.w, a3.x, a3.y, a3.z, a3.w};
            float bv[4] = {Bs[k][tx], Bs[k][tx + 64], Bs[k][tx + 128], Bs[k][tx + 192]};
#pragma unroll
            for (int i = 0; i < 16; i++)
#pragma unroll
                for (int j = 0; j < 4; j++) acc[i][j] += av[i] * bv[j];
        }
        __syncthreads();
    }
#pragma unroll
    for (int i = 0; i < 16; i++) {
        int m = m0 + ty * 16 + i;
#pragma unroll
        for (int j = 0; j < 4; j++) {
            int n = tx + 64 * j;
            if (n < DD) atomicAdd(&fc_acc[(size_t)m * DD + n], acc[i][j]);
        }
    }
}

// ---------------- bn2 stats over batch per feature ----------------
__global__ void bn2_stats_kernel(const float* __restrict__ fc_acc, const float* __restrict__ fc_b,
                                 float* __restrict__ sum, float* __restrict__ sq) {
    int f = blockIdx.x;      // 200
    int lane = threadIdx.x;  // 64
    float s = 0.f, q = 0.f;
    float bb = fc_b[f];
    for (int b = lane; b < BATCH; b += 64) {
        float v = fc_acc[(size_t)b * DD + f] + bb;
        s += v; q += v * v;
    }
    for (int o = 32; o > 0; o >>= 1) {
        s += __shfl_down(s, o, 64);
        q += __shfl_down(q, o, 64);
    }
    if (lane == 0) { sum[f] = s; sq[f] = q; }
}

__global__ void hfin_kernel(const float* __restrict__ fc_acc, const float* __restrict__ fc_b,
                            const float* __restrict__ sum, const float* __restrict__ sq,
                            const float* __restrict__ g2, const float* __restrict__ b2,
                            float* __restrict__ hfin) {
    int e = blockIdx.x * blockDim.x + threadIdx.x;
    if (e >= BATCH * DD) return;
    int f = e % DD;
    float m = sum[f] * (1.0f / BATCH);
    float var = sq[f] * (1.0f / BATCH) - m * m;
    float v = (fc_acc[e] + fc_b[f] - m) * rsqrtf(var + EPSV) * g2[f] + b2[f];
    hfin[e] = fmaxf(v, 0.f);
}

// ---------------- logits GEMM v3: 128x128 tile, double-buffered, split-B banks ----------------
__launch_bounds__(256, 2)
__global__ void gemm_logits(const float* __restrict__ hfin, const float* __restrict__ x2,
                            const float* __restrict__ ent_bias, float* __restrict__ out) {
    __shared__ float As[2][8][132];
    __shared__ float Bs[2][8][132];
    const int m0 = blockIdx.x * 128;
    const int n0 = blockIdx.y * 128;
    const int tid = threadIdx.x;
    const int tx = tid & 15, ty = tid >> 4;
    const int lr  = tid >> 1;          // 0..127
    const int lkc = (tid & 1) * 4;     // 0,4
    const int gn = n0 + lr;
    const bool nval = gn < N_ENTS;

    auto loadA = [&](int k0) -> float4 {
        return *(const float4*)&hfin[(size_t)(m0 + lr) * DD + k0 + lkc];
    };
    auto loadB = [&](int k0) -> float4 {
        float4 v = make_float4(0.f, 0.f, 0.f, 0.f);
        if (nval) v = *(const float4*)&x2[(size_t)gn * DD + k0 + lkc];
        return v;
    };
    auto stage = [&](float4 va, float4 vb, int buf) {
        As[buf][lkc + 0][lr] = va.x; As[buf][lkc + 1][lr] = va.y;
        As[buf][lkc + 2][lr] = va.z; As[buf][lkc + 3][lr] = va.w;
        Bs[buf][lkc + 0][lr] = vb.x; Bs[buf][lkc + 1][lr] = vb.y;
        Bs[buf][lkc + 2][lr] = vb.z; Bs[buf][lkc + 3][lr] = vb.w;
    };

    float acc[8][8] = {};
    stage(loadA(0), loadB(0), 0);
    __syncthreads();
    int cur = 0;

    for (int k0 = 0; k0 < DD; k0 += 8) {
        const int nxt = k0 + 8;
        const bool have = nxt < DD;
        float4 na = make_float4(0.f, 0.f, 0.f, 0.f), nb = na;
        if (have) { na = loadA(nxt); nb = loadB(nxt); }
#pragma unroll
        for (int k = 0; k < 8; k++) {
            float4 a0 = *(const float4*)&As[cur][k][ty * 8];
            float4 a1 = *(const float4*)&As[cur][k][ty * 8 + 4];
            float4 b0 = *(const float4*)&Bs[cur][k][tx * 4];
            float4 b1 = *(const float4*)&Bs[cur][k][64 + tx * 4];
            float av[8] = {a0.x, a0.y, a0.z, a0.w, a1.x, a1.y, a1.z, a1.w};
            float bv[8] = {b0.x, b0.y, b0.z, b0.w, b1.x, b1.y, b1.z, b1.w};
#pragma unroll
            for (int i = 0; i < 8; i++)
#pragma unroll
                for (int j = 0; j < 8; j++) acc[i][j] += av[i] * bv[j];
        }
        if (have) {
            stage(na, nb, cur ^ 1);
            __syncthreads();
            cur ^= 1;
        }
    }

    const int nb0 = n0 + tx * 4;
    const int nb1 = n0 + 64 + tx * 4;
    const bool v0 = (nb0 + 3) < N_ENTS;
    const bool v1 = (nb1 + 3) < N_ENTS;
    float4 e0 = make_float4(0.f, 0.f, 0.f, 0.f), e1 = e0;
    if (v0) e0 = *(const float4*)&ent_bias[nb0];
    if (v1) e1 = *(const float4*)&ent_bias[nb1];
    float eb[8] = {e0.x, e0.y, e0.z, e0.w, e1.x, e1.y, e1.z, e1.w};
#pragma unroll
    for (int i = 0; i < 8; i++) {
        int m = m0 + ty * 8 + i;   // always < BATCH
        float o[8];
#pragma unroll
        for (int j = 0; j < 8; j++) {
            float v = acc[i][j] + eb[j];
            o[j] = 1.0f / (1.0f + __expf(-v));
        }
        if (v0) *(float4*)&out[(size_t)m * N_ENTS + nb0] = make_float4(o[0], o[1], o[2], o[3]);
        if (v1) *(float4*)&out[(size_t)m * N_ENTS + nb1] = make_float4(o[4], o[5], o[6], o[7]);
    }
}

// ================= host launch =================
extern "C" void kernel_launch(void* const* d_in, const int* in_sizes, int n_in,
                              void* d_out, int out_size, void* d_ws, size_t ws_size,
                              hipStream_t stream) {
    const int*   sub        = (const int*)d_in[0];
    const int*   rel        = (const int*)d_in[1];
    const int*   edge_index = (const int*)d_in[2];
    const int*   edge_type  = (const int*)d_in[3];
    const float* init_embed = (const float*)d_in[4];
    const float* init_rel   = (const float*)d_in[5];
    const float* w_in1      = (const float*)d_in[6];
    const float* w_out1     = (const float*)d_in[7];
    const float* w_loop1    = (const float*)d_in[8];
    const float* w_rel1     = (const float*)d_in[9];
    const float* loop_rel1  = (const float*)d_in[10];
    const float* bn_g1      = (const float*)d_in[11];
    const float* bn_b1      = (const float*)d_in[12];
    const float* w_in2      = (const float*)d_in[13];
    const float* w_out2     = (const float*)d_in[14];
    const float* w_loop2    = (const float*)d_in[15];
    const float* w_rel2     = (const float*)d_in[16];
    const float* loop_rel2  = (const float*)d_in[17];
    const float* bn_g2      = (const float*)d_in[18];
    const float* bn_b2      = (const float*)d_in[19];
    const float* conv_w     = (const float*)d_in[20];
    const float* bn0_g      = (const float*)d_in[21];
    const float* bn0_b      = (const float*)d_in[22];
    const float* bn1_g      = (const float*)d_in[23];
    const float* bn1_b      = (const float*)d_in[24];
    const float* bn2_g      = (const float*)d_in[25];
    const float* bn2_b      = (const float*)d_in[26];
    const float* fc_w       = (const float*)d_in[27];
    const float* fc_b       = (const float*)d_in[28];
    const float* ent_bias   = (const float*)d_in[29];

    float* ws = (float*)d_ws;
    float* x1       = ws + WS_X1;
    float* x2       = ws + WS_X2;
    float* r1       = ws + WS_R1;
    float* r2       = ws + WS_R2;
    float* dinv_in  = ws + WS_DINV_IN;
    float* dinv_out = ws + WS_DINV_OUT;
    float* stats    = ws + WS_STATS;
    float* imgraw   = ws + WS_IMGRAW;
    float* fc_acc   = ws + WS_FCACC;
    float* hfin     = ws + WS_HFIN;
    float* big      = ws + WS_BIG;   // agg1 (10M) / agg2 (20M) / conv_raw (20.07M)
    float* out      = (float*)d_out;

    // CSR sort scratch lives in the x2 region (free until gemm_layer<200> writes x2)
    int*  cnt    = (int*)x2;                       // NKEY
    int*  startp = cnt + NKEY;                     // NKEY+1
    int4* rec    = (int4*)(cnt + 2 * NKEY + 8);    // E_TOT records, 16B-aligned

    // zero accumulators (ws is poisoned 0xAA before every call)
    hipMemsetAsync(stats, 0, 4096 * sizeof(float), stream);
    hipMemsetAsync(fc_acc, 0, BATCH * DD * sizeof(float), stream);
    hipMemsetAsync(cnt, 0, NKEY * sizeof(int), stream);

    // CSR build (once; reused by both layers). degrees come from the histogram.
    hist_kernel<<<(E_TOT + 255) / 256, 256, 0, stream>>>(edge_index, cnt);
    dinv_kernel<<<(N_ENTS + 255) / 256, 256, 0, stream>>>(cnt, dinv_in, dinv_out);
    scan_kernel<<<1, 1024, 0, stream>>>(cnt, startp);
    fill_kernel<<<(E_TOT + 255) / 256, 256, 0, stream>>>(edge_index, edge_type,
                                                         dinv_in, dinv_out, startp, rec);

    // ---- layer 1 ----  (agg stride 200 = in|out halves; loop fused into gemm)
    seg_kernel<100, 200><<<NKEY, 128, 0, stream>>>(startp, cnt, rec, init_embed, init_rel, big);
    {
        dim3 g((N_ENTS + 127) / 128, (DD + 127) / 128);
        gemm_layer<100><<<g, 256, 0, stream>>>(big, init_embed, loop_rel1,
                                               w_in1, w_out1, w_loop1, dinv_in, dinv_out, x1);
    }
    feat_stats_kernel<<<256, 256, 0, stream>>>(x1, N_ENTS, stats + ST_L1_SUM, stats + ST_L1_SQ);
    layer_apply_kernel<<<(N_ENTS * DD + 255) / 256, 256, 0, stream>>>(x1, stats + ST_L1_SUM,
                                                                      stats + ST_L1_SQ, bn_g1, bn_b1);
    rel_kernel<100><<<N_RELS, 256, 0, stream>>>(init_rel, w_rel1, r1);

    // ---- layer 2 ----  (agg stride 400)
    seg_kernel<200, 400><<<NKEY, 256, 0, stream>>>(startp, cnt, rec, x1, r1, big);
    {
        dim3 g((N_ENTS + 127) / 128, (DD + 127) / 128);
        gemm_layer<200><<<g, 256, 0, stream>>>(big, x1, loop_rel2,
                                               w_in2, w_out2, w_loop2, dinv_in, dinv_out, x2);
    }
    feat_stats_kernel<<<256, 256, 0, stream>>>(x2, N_ENTS, stats + ST_L2_SUM, stats + ST_L2_SQ);
    layer_apply_kernel<<<(N_ENTS * DD + 255) / 256, 256, 0, stream>>>(x2, stats + ST_L2_SUM,
                                                                      stats + ST_L2_SQ, bn_g2, bn_b2);
    rel_kernel<200><<<N_RELS, 256, 0, stream>>>(r1, w_rel2, r2);

    // ---- ConvE scorer ----
    gather_kernel<<<BATCH, 512, 0, stream>>>(sub, rel, x2, r2, imgraw, stats + ST_BN0);
    conv_kernel<<<BATCH, 256, 0, stream>>>(imgraw, stats + ST_BN0, bn0_g, bn0_b, conv_w, big);
    bn1_stats_kernel<<<BATCH * NFILT, 64, 0, stream>>>(big, stats + ST_BN1_SUM, stats + ST_BN1_SQ);
    bn1_coef_kernel<<<1, 256, 0, stream>>>(stats + ST_BN1_SUM, stats + ST_BN1_SQ, bn1_g, bn1_b,
                                           stats + ST_S1, stats + ST_T1);
    {
        dim3 g(BATCH / 64, 49);   // split-K: 49 chunks of 800
        gemm_fc<<<g, 256, 0, stream>>>(big, fc_w, stats + ST_S1, stats + ST_T1, fc_acc);
    }
    bn2_stats_kernel<<<NFILT, 64, 0, stream>>>(fc_acc, fc_b, stats + ST_BN2_SUM, stats + ST_BN2_SQ);
    hfin_kernel<<<(BATCH * DD + 255) / 256, 256, 0, stream>>>(fc_acc, fc_b, stats + ST_BN2_SUM,
                                                              stats + ST_BN2_SQ, bn2_g, bn2_b, hfin);
    {
        dim3 g(BATCH / 128, (N_ENTS + 127) / 128);
        gemm_logits<<<g, 256, 0, stream>>>(hfin, x2, ent_bias, out);
    }
}

// Round 7
// 1874.664 us; speedup vs baseline: 1.0565x; 1.0565x over previous
//
#include <hip/hip_runtime.h>
#include <math.h>

#define N_ENTS   50000
#define N_RELS   400        // 2*N_REL
#define D_IN0    100
#define DD       200
#define E_DIR    250000
#define E_TOT    500000
#define BATCH    512
#define NFILT    200
#define FLATK    39200
#define EPSV     1e-5f
#define NKEY     (2 * N_ENTS)   // (side, row) keys: in rows [0,50000), out rows [50000,100000)

// ---------------- workspace layout (float offsets) ----------------
#define WS_X1      ((size_t)0)
#define WS_X2      ((size_t)10000000)
#define WS_R1      ((size_t)20000000)
#define WS_R2      ((size_t)20080000)
#define WS_DINV_IN ((size_t)20160000)
#define WS_DINV_OUT ((size_t)20210000)
#define WS_STATS   ((size_t)20260000)   // 4096 floats
// stats sublayout
#define ST_L1_SUM   0
#define ST_L1_SQ    200
#define ST_L2_SUM   400
#define ST_L2_SQ    600
#define ST_BN0      800   // [0]=sum [1]=sq
#define ST_BN1_SUM  802
#define ST_BN1_SQ   1002
#define ST_BN2_SUM  1202
#define ST_BN2_SQ   1402
#define ST_S1       1602
#define ST_T1       1802
#define WS_IMGRAW  ((size_t)20264096)   // 512*400
#define WS_FCACC   ((size_t)20673696)   // 512*200
#define WS_HFIN    ((size_t)20776096)   // 512*200
#define WS_BIG     ((size_t)20878528)   // 30,000,000 floats (agg + K-half scratch / conv_raw)

// ---------------- dinv from histogram counts ----------------
__global__ void dinv_kernel(const int* __restrict__ cnt, float* dinv_in, float* dinv_out) {
    int i = blockIdx.x * blockDim.x + threadIdx.x;
    if (i >= N_ENTS) return;
    int a = cnt[i];
    dinv_in[i]  = (a > 0) ? rsqrtf((float)a) : 0.f;
    int b = cnt[N_ENTS + i];
    dinv_out[i] = (b > 0) ? rsqrtf((float)b) : 0.f;
}

// ---------------- CSR build: histogram -> scan -> fill ----------------
__global__ void hist_kernel(const int* __restrict__ ei, int* __restrict__ cnt) {
    int e = blockIdx.x * blockDim.x + threadIdx.x;
    if (e >= E_TOT) return;
    int key = ei[e] + ((e < E_DIR) ? 0 : N_ENTS);
    atomicAdd(&cnt[key], 1);
}

// single-block exclusive scan of cnt[NKEY] -> startp[NKEY+1]
__global__ __launch_bounds__(1024) void scan_kernel(const int* __restrict__ cnt,
                                                    int* __restrict__ startp) {
    __shared__ int part[1024];
    const int tid = threadIdx.x;
    const int per = (NKEY + 1023) / 1024;   // 98
    int b = tid * per;
    int e = b + per; if (e > NKEY) e = NKEY;
    if (b > NKEY) b = NKEY;
    int s = 0;
    for (int i = b; i < e; i++) s += cnt[i];
    part[tid] = s;
    __syncthreads();
    for (int off = 1; off < 1024; off <<= 1) {
        int v = (tid >= off) ? part[tid - off] : 0;
        __syncthreads();
        part[tid] += v;
        __syncthreads();
    }
    int run = (tid == 0) ? 0 : part[tid - 1];
    for (int i = b; i < e; i++) { startp[i] = run; run += cnt[i]; }
    if (e == NKEY) startp[NKEY] = run;
}

// fill sorted edge records (col, type, dinv_side[col], pad); advances startp[key] to END
__global__ void fill_kernel(const int* __restrict__ ei, const int* __restrict__ et,
                            const float* __restrict__ dinv_in, const float* __restrict__ dinv_out,
                            int* __restrict__ startp, int4* __restrict__ rec) {
    int e = blockIdx.x * blockDim.x + threadIdx.x;
    if (e >= E_TOT) return;
    bool in_side = e < E_DIR;
    int key = ei[e] + (in_side ? 0 : N_ENTS);
    int pos = atomicAdd(&startp[key], 1);
    int col = ei[E_TOT + e];
    float sc = in_side ? dinv_in[col] : dinv_out[col];
    rec[pos] = make_int4(col, et[e], __float_as_int(sc), 0);
}

// ---------------- segmented reduction: agg[row, side] = sum over edges ----------------
template<int DIN, int STRIDE>
__global__ void seg_kernel(const int* __restrict__ startp, const int* __restrict__ cnt,
                           const int4* __restrict__ rec,
                           const float* __restrict__ x, const float* __restrict__ r,
                           float* __restrict__ agg) {
    int key = blockIdx.x;
    int d = threadIdx.x;
    if (d >= DIN) return;
    int end = startp[key];
    int beg = end - cnt[key];
    bool in_side = key < N_ENTS;
    int row = in_side ? key : key - N_ENTS;
    float acc = 0.f;
    if (beg < end) {
        int4 rc = rec[beg];
        for (int p = beg; p + 1 < end; p++) {
            int4 nx = rec[p + 1];
            acc += x[(size_t)rc.x * DIN + d] * r[(size_t)rc.y * DIN + d] * __int_as_float(rc.z);
            rc = nx;
        }
        acc += x[(size_t)rc.x * DIN + d] * r[(size_t)rc.y * DIN + d] * __int_as_float(rc.z);
    }
    agg[(size_t)row * STRIDE + (in_side ? 0 : DIN) + d] = acc;
}

// ---------------- layer GEMM v6: BK=8 dbuf, split-B, fused loop-compose, SPLIT-K z=2 ----------------
// z=0 computes k in [0,C0), z=1 computes [C0,K); halves go to out0/out1 and are
// summed in feat_stats/layer_apply (fp32 reassociation only).
template<int DIN>
__launch_bounds__(256, 2)
__global__ void gemm_layer(const float* __restrict__ agg,
                           const float* __restrict__ x, const float* __restrict__ loop_rel,
                           const float* __restrict__ w_in, const float* __restrict__ w_out,
                           const float* __restrict__ w_loop,
                           const float* __restrict__ dinv_in, const float* __restrict__ dinv_out,
                           float* __restrict__ out0, float* __restrict__ out1) {
    const int K  = 3 * DIN;
    const int C0 = ((3 * DIN / 2 + 7) / 8) * 8;   // 152 (DIN=100) / 304 (DIN=200)
    const int z    = blockIdx.z;
    const int kbeg = z ? C0 : 0;
    const int kend = z ? K  : C0;
    float* out = z ? out1 : out0;

    __shared__ float As[2][8][132];   // [buf][k][m]
    __shared__ float Bs[2][8][132];   // [buf][k][n]
    const int m0 = blockIdx.x * 128;
    const int n0 = blockIdx.y * 128;
    const int tid = threadIdx.x;
    const int tx = tid & 15, ty = tid >> 4;
    const int am  = tid >> 1;          // A row 0..127
    const int akc = (tid & 1) * 4;     // A k-offset 0,4
    const int bk = tid >> 5;           // B k 0..7
    const int bn = (tid & 31) * 4;     // B n-offset 0..124

    const int gm = m0 + am;
    const bool mval = gm < N_ENTS;
    const float scin  = mval ? dinv_in[gm]  : 0.f;
    const float scout = mval ? dinv_out[gm] : 0.f;
    const float* arow = &agg[(size_t)gm * (2 * DIN)];
    const float* xrow = &x[(size_t)gm * DIN];
    const bool bnval = (n0 + bn + 3) < DD;

    // 4-groups never straddle region boundaries (DIN, 2*DIN, C0 are %4==0)
    auto loadA = [&](int k0) -> float4 {
        int kg = k0 + akc;
        float4 v = make_float4(0.f, 0.f, 0.f, 0.f);
        if (mval && kg < kend) {
            if (kg < 2 * DIN) {
                v = *(const float4*)&arow[kg];
            } else {
                int kk = kg - 2 * DIN;
                float4 xv = *(const float4*)&xrow[kk];
                float4 lv = *(const float4*)&loop_rel[kk];
                v = make_float4(xv.x * lv.x, xv.y * lv.y, xv.z * lv.z, xv.w * lv.w);
            }
        }
        return v;
    };
    auto loadB = [&](int k0) -> float4 {
        int kg = k0 + bk;
        float4 v = make_float4(0.f, 0.f, 0.f, 0.f);
        if (kg < kend && bnval) {
            const float* wsrc; int kk;
            if (kg < DIN)          { wsrc = w_in;   kk = kg; }
            else if (kg < 2 * DIN) { wsrc = w_out;  kk = kg - DIN; }
            else                   { wsrc = w_loop; kk = kg - 2 * DIN; }
            v = *(const float4*)&wsrc[(size_t)kk * DD + n0 + bn];
        }
        return v;
    };
    auto stageA = [&](int k0, float4 v, int buf) {
        int kg = k0 + akc;
        float s = (kg < DIN) ? scin : ((kg < 2 * DIN) ? scout : 1.0f);
        As[buf][akc + 0][am] = v.x * s;
        As[buf][akc + 1][am] = v.y * s;
        As[buf][akc + 2][am] = v.z * s;
        As[buf][akc + 3][am] = v.w * s;
    };
    auto stageB = [&](float4 v, int buf) {
        *(float4*)&Bs[buf][bk][bn] = v;
    };

    float acc[8][8] = {};

    stageA(kbeg, loadA(kbeg), 0);
    stageB(loadB(kbeg), 0);
    __syncthreads();
    int cur = 0;

    for (int k0 = kbeg; k0 < kend; k0 += 8) {
        const int nxt = k0 + 8;
        const bool have = nxt < kend;
        float4 na = make_float4(0.f, 0.f, 0.f, 0.f), nb = na;
        if (have) { na = loadA(nxt); nb = loadB(nxt); }
#pragma unroll
        for (int k = 0; k < 8; k++) {
            float4 a0 = *(const float4*)&As[cur][k][ty * 8];
            float4 a1 = *(const float4*)&As[cur][k][ty * 8 + 4];
            float4 b0 = *(const float4*)&Bs[cur][k][tx * 4];
            float4 b1 = *(const float4*)&Bs[cur][k][64 + tx * 4];
            float av[8] = {a0.x, a0.y, a0.z, a0.w, a1.x, a1.y, a1.z, a1.w};
            float bv[8] = {b0.x, b0.y, b0.z, b0.w, b1.x, b1.y, b1.z, b1.w};
#pragma unroll
            for (int i = 0; i < 8; i++)
#pragma unroll
                for (int j = 0; j < 8; j++) acc[i][j] += av[i] * bv[j];
        }
        if (have) {
            stageA(nxt, na, cur ^ 1);
            stageB(nb, cur ^ 1);
            __syncthreads();
            cur ^= 1;
        }
    }

    const int nb0 = n0 + tx * 4;
    const int nb1 = n0 + 64 + tx * 4;
    const bool v0 = (nb0 + 3) < DD;
    const bool v1 = (nb1 + 3) < DD;
#pragma unroll
    for (int i = 0; i < 8; i++) {
        int m = m0 + ty * 8 + i;
        if (m < N_ENTS) {
            if (v0) *(float4*)&out[(size_t)m * DD + nb0] = make_float4(acc[i][0], acc[i][1], acc[i][2], acc[i][3]);
            if (v1) *(float4*)&out[(size_t)m * DD + nb1] = make_float4(acc[i][4], acc[i][5], acc[i][6], acc[i][7]);
        }
    }
}

// ---------------- per-feature stats over (a+b): thread owns column f ----------------
__global__ void feat_stats_kernel(const float* __restrict__ a, const float* __restrict__ b,
                                  int n_rows, float* __restrict__ sum, float* __restrict__ sq) {
    int f = threadIdx.x;            // 256 threads, active < 200
    if (f >= DD) return;
    int rows_per = (n_rows + gridDim.x - 1) / gridDim.x;
    int r0 = blockIdx.x * rows_per;
    int r1 = r0 + rows_per; if (r1 > n_rows) r1 = n_rows;
    float s = 0.f, q = 0.f;
    for (int rr = r0; rr < r1; rr++) {
        size_t idx = (size_t)rr * DD + f;
        float v = a[idx] + b[idx];
        s += v; q += v * v;
    }
    atomicAdd(&sum[f], s);
    atomicAdd(&sq[f], q);
}

// ---------------- BN over nodes of (a+b)/3 + tanh; result into a ----------------
__global__ void layer_apply_kernel(float* __restrict__ x, const float* __restrict__ xb,
                                   const float* __restrict__ sum, const float* __restrict__ sq,
                                   const float* __restrict__ g, const float* __restrict__ b) {
    int e = blockIdx.x * blockDim.x + threadIdx.x;
    if (e >= N_ENTS * DD) return;
    int f = e % DD;
    float mean = sum[f] * (1.0f / (3.0f * N_ENTS));
    float msq  = sq[f] * (1.0f / (9.0f * (float)N_ENTS));
    float var = msq - mean * mean;
    float t = x[e] + xb[e];
    float v = (t * (1.0f / 3.0f) - mean) * rsqrtf(var + EPSV) * g[f] + b[f];
    x[e] = tanhf(v);
}

// ---------------- relation transform: rout[400,200] = rprev[400,K] @ w_rel[K,200] ----------------
template<int KDIM>
__global__ void rel_kernel(const float* __restrict__ rprev, const float* __restrict__ w_rel,
                           float* __restrict__ rout) {
    int i = blockIdx.x;       // 0..399
    int j = threadIdx.x;      // 256, active < 200
    if (j >= DD) return;
    float acc = 0.f;
    for (int k = 0; k < KDIM; k++)
        acc += rprev[(size_t)i * KDIM + k] * w_rel[(size_t)k * DD + j];
    rout[(size_t)i * DD + j] = acc;
}

// ---------------- gather sub/rel embeddings into image + bn0 stats ----------------
__global__ void gather_kernel(const int* __restrict__ sub, const int* __restrict__ rel,
                              const float* __restrict__ x2, const float* __restrict__ r2,
                              float* __restrict__ imgraw, float* __restrict__ bn0acc) {
    int b = blockIdx.x;       // 512
    int t = threadIdx.x;      // 512
    float v = 0.f;
    if (t < 400) {
        int d = t >> 1;
        v = (t & 1) ? r2[(size_t)rel[b] * DD + d] : x2[(size_t)sub[b] * DD + d];
        imgraw[b * 400 + t] = v;
    }
    float sqv = v * v;
    for (int o = 32; o > 0; o >>= 1) {
        v   += __shfl_down(v, o, 64);
        sqv += __shfl_down(sqv, o, 64);
    }
    __shared__ float s1[8], s2l[8];
    int wid = t >> 6, lane = t & 63;
    if (lane == 0) { s1[wid] = v; s2l[wid] = sqv; }
    __syncthreads();
    if (t == 0) {
        float a = 0.f, c = 0.f;
        for (int w = 0; w < 8; w++) { a += s1[w]; c += s2l[w]; }
        atomicAdd(&bn0acc[0], a);
        atomicAdd(&bn0acc[1], c);
    }
}

// ---------------- conv 7x7 VALID, fused bn0, 4-way filter split ----------------
// grid (512, 4): block handles batch b, filters [blockIdx.y*50, +50)
__global__ void conv_kernel(const float* __restrict__ imgraw, const float* __restrict__ bn0acc,
                            const float* __restrict__ g0, const float* __restrict__ b0,
                            const float* __restrict__ conv_w, float* __restrict__ conv_raw) {
    __shared__ float simg[400];
    __shared__ float sw[2450];        // 50 filters x 49
    int b  = blockIdx.x;
    int fb = blockIdx.y * 50;
    int t  = threadIdx.x;  // 256
    const float inv_n = 1.0f / (BATCH * 400);
    float m = bn0acc[0] * inv_n;
    float var = bn0acc[1] * inv_n - m * m;
    float rs = rsqrtf(var + EPSV);
    float g0v = g0[0], b0v = b0[0];
    for (int i = t; i < 400; i += 256)
        simg[i] = (imgraw[b * 400 + i] - m) * rs * g0v + b0v;
    for (int i = t; i < 2450; i += 256) sw[i] = conv_w[fb * 49 + i];
    __syncthreads();
    const size_t obase = (size_t)b * FLATK + (size_t)fb * 196;
    for (int o = t; o < 9800; o += 256) {
        int f = o / 196;            // local filter 0..49
        int ij = o % 196;
        int i = ij / 14, j = ij % 14;
        const float* wp = &sw[f * 49];
        const float* ip = &simg[i * 20 + j];
        float acc = 0.f;
#pragma unroll
        for (int p = 0; p < 7; p++)
#pragma unroll
            for (int q = 0; q < 7; q++)
                acc += ip[p * 20 + q] * wp[p * 7 + q];
        conv_raw[obase + o] = acc;
    }
}

// ---------------- bn1 stats: per-filter sum/sq over (b, i, j) ----------------
__global__ void bn1_stats_kernel(const float* __restrict__ conv_raw,
                                 float* __restrict__ sum, float* __restrict__ sq) {
    int blk = blockIdx.x;          // b*200 + f, 102400 blocks
    int f = blk % 200;
    size_t base = (size_t)blk * 196;
    int lane = threadIdx.x;        // 64
    float s = 0.f, q = 0.f;
    for (int i = lane; i < 196; i += 64) {
        float v = conv_raw[base + i];
        s += v; q += v * v;
    }
    for (int o = 32; o > 0; o >>= 1) {
        s += __shfl_down(s, o, 64);
        q += __shfl_down(q, o, 64);
    }
    if (lane == 0) { atomicAdd(&sum[f], s); atomicAdd(&sq[f], q); }
}

__global__ void bn1_coef_kernel(const float* __restrict__ sum, const float* __restrict__ sq,
                                const float* __restrict__ g1, const float* __restrict__ b1,
                                float* __restrict__ s1, float* __restrict__ t1) {
    int f = threadIdx.x;
    if (f >= 200) return;
    const float inv_n = 1.0f / (BATCH * 196);
    float m = sum[f] * inv_n;
    float var = sq[f] * inv_n - m * m;
    float s = g1[f] * rsqrtf(var + EPSV);
    s1[f] = s;
    t1[f] = b1[f] - m * s;
}

// ---------------- FC GEMM: M=64 x N=200(full) x BK=32, split-K Z=49 ----------------
__global__ void gemm_fc(const float* __restrict__ conv_raw, const float* __restrict__ fc_w,
                        const float* __restrict__ s1g, const float* __restrict__ t1g,
                        float* __restrict__ fc_acc) {
    __shared__ float As[32][68];
    __shared__ float Bs[32][256];
    __shared__ float Ss1[200], St1[200];
    const int m0   = blockIdx.x * 64;
    const int kbeg = blockIdx.y * 800;
    const int tid  = threadIdx.x;
    const int tx = tid & 63, ty = tid >> 6;
    const int ar  = tid >> 2;
    const int akc = (tid & 3) * 8;

    for (int i = tid; i < 200; i += 256) { Ss1[i] = s1g[i]; St1[i] = t1g[i]; }
    __syncthreads();

    float acc[16][4] = {};
    for (int k0 = 0; k0 < 800; k0 += 32) {
        {
            const float4* gp = (const float4*)&conv_raw[(size_t)(m0 + ar) * FLATK + kbeg + k0 + akc];
            float4 v0 = gp[0], v1 = gp[1];
            float tmp[8] = {v0.x, v0.y, v0.z, v0.w, v1.x, v1.y, v1.z, v1.w};
#pragma unroll
            for (int j = 0; j < 8; j++) {
                int kg = kbeg + k0 + akc + j;
                int f = kg / 196;
                As[akc + j][ar] = fmaxf(tmp[j] * Ss1[f] + St1[f], 0.f);
            }
        }
        {
            const float4* gp = (const float4*)&fc_w[(size_t)(kbeg + k0) * 200];
            for (int idx = tid; idx < 1600; idx += 256) {
                float4 v = gp[idx];
                int k = idx / 50, n4 = (idx % 50) * 4;
                *(float4*)&Bs[k][n4] = v;
            }
        }
        __syncthreads();
#pragma unroll 4
        for (int k = 0; k < 32; k++) {
            float4 a0 = *(const float4*)&As[k][ty * 16];
            float4 a1 = *(const float4*)&As[k][ty * 16 + 4];
            float4 a2 = *(const float4*)&As[k][ty * 16 + 8];
            float4 a3 = *(const float4*)&As[k][ty * 16 + 12];
            float av[16] = {a0.x, a0.y, a0.z, a0.w, a1.x, a1.y, a1.z, a1.w,
                            a2.x, a2.y, a2.z, a2.w, a3.x, a3.y, a3.z, a3.w};
            float bv[4] = {Bs[k][tx], Bs[k][tx + 64], Bs[k][tx + 128], Bs[k][tx + 192]};
#pragma unroll
            for (int i = 0; i < 16; i++)
#pragma unroll
                for (int j = 0; j < 4; j++) acc[i][j] += av[i] * bv[j];
        }
        __syncthreads();
    }
#pragma unroll
    for (int i = 0; i < 16; i++) {
        int m = m0 + ty * 16 + i;
#pragma unroll
        for (int j = 0; j < 4; j++) {
            int n = tx + 64 * j;
            if (n < DD) atomicAdd(&fc_acc[(size_t)m * DD + n], acc[i][j]);
        }
    }
}

// ---------------- bn2 stats over batch per feature ----------------
__global__ void bn2_stats_kernel(const float* __restrict__ fc_acc, const float* __restrict__ fc_b,
                                 float* __restrict__ sum, float* __restrict__ sq) {
    int f = blockIdx.x;      // 200
    int lane = threadIdx.x;  // 64
    float s = 0.f, q = 0.f;
    float bb = fc_b[f];
    for (int b = lane; b < BATCH; b += 64) {
        float v = fc_acc[(size_t)b * DD + f] + bb;
        s += v; q += v * v;
    }
    for (int o = 32; o > 0; o >>= 1) {
        s += __shfl_down(s, o, 64);
        q += __shfl_down(q, o, 64);
    }
    if (lane == 0) { sum[f] = s; sq[f] = q; }
}

__global__ void hfin_kernel(const float* __restrict__ fc_acc, const float* __restrict__ fc_b,
                            const float* __restrict__ sum, const float* __restrict__ sq,
                            const float* __restrict__ g2, const float* __restrict__ b2,
                            float* __restrict__ hfin) {
    int e = blockIdx.x * blockDim.x + threadIdx.x;
    if (e >= BATCH * DD) return;
    int f = e % DD;
    float m = sum[f] * (1.0f / BATCH);
    float var = sq[f] * (1.0f / BATCH) - m * m;
    float v = (fc_acc[e] + fc_b[f] - m) * rsqrtf(var + EPSV) * g2[f] + b2[f];
    hfin[e] = fmaxf(v, 0.f);
}

// ---------------- logits GEMM: 128x128 tile, double-buffered, split-B banks ----------------
__launch_bounds__(256, 2)
__global__ void gemm_logits(const float* __restrict__ hfin, const float* __restrict__ x2,
                            const float* __restrict__ ent_bias, float* __restrict__ out) {
    __shared__ float As[2][8][132];
    __shared__ float Bs[2][8][132];
    const int m0 = blockIdx.x * 128;
    const int n0 = blockIdx.y * 128;
    const int tid = threadIdx.x;
    const int tx = tid & 15, ty = tid >> 4;
    const int lr  = tid >> 1;          // 0..127
    const int lkc = (tid & 1) * 4;     // 0,4
    const int gn = n0 + lr;
    const bool nval = gn < N_ENTS;

    auto loadA = [&](int k0) -> float4 {
        return *(const float4*)&hfin[(size_t)(m0 + lr) * DD + k0 + lkc];
    };
    auto loadB = [&](int k0) -> float4 {
        float4 v = make_float4(0.f, 0.f, 0.f, 0.f);
        if (nval) v = *(const float4*)&x2[(size_t)gn * DD + k0 + lkc];
        return v;
    };
    auto stage = [&](float4 va, float4 vb, int buf) {
        As[buf][lkc + 0][lr] = va.x; As[buf][lkc + 1][lr] = va.y;
        As[buf][lkc + 2][lr] = va.z; As[buf][lkc + 3][lr] = va.w;
        Bs[buf][lkc + 0][lr] = vb.x; Bs[buf][lkc + 1][lr] = vb.y;
        Bs[buf][lkc + 2][lr] = vb.z; Bs[buf][lkc + 3][lr] = vb.w;
    };

    float acc[8][8] = {};
    stage(loadA(0), loadB(0), 0);
    __syncthreads();
    int cur = 0;

    for (int k0 = 0; k0 < DD; k0 += 8) {
        const int nxt = k0 + 8;
        const bool have = nxt < DD;
        float4 na = make_float4(0.f, 0.f, 0.f, 0.f), nb = na;
        if (have) { na = loadA(nxt); nb = loadB(nxt); }
#pragma unroll
        for (int k = 0; k < 8; k++) {
            float4 a0 = *(const float4*)&As[cur][k][ty * 8];
            float4 a1 = *(const float4*)&As[cur][k][ty * 8 + 4];
            float4 b0 = *(const float4*)&Bs[cur][k][tx * 4];
            float4 b1 = *(const float4*)&Bs[cur][k][64 + tx * 4];
            float av[8] = {a0.x, a0.y, a0.z, a0.w, a1.x, a1.y, a1.z, a1.w};
            float bv[8] = {b0.x, b0.y, b0.z, b0.w, b1.x, b1.y, b1.z, b1.w};
#pragma unroll
            for (int i = 0; i < 8; i++)
#pragma unroll
                for (int j = 0; j < 8; j++) acc[i][j] += av[i] * bv[j];
        }
        if (have) {
            stage(na, nb, cur ^ 1);
            __syncthreads();
            cur ^= 1;
        }
    }

    const int nb0 = n0 + tx * 4;
    const int nb1 = n0 + 64 + tx * 4;
    const bool v0 = (nb0 + 3) < N_ENTS;
    const bool v1 = (nb1 + 3) < N_ENTS;
    float4 e0 = make_float4(0.f, 0.f, 0.f, 0.f), e1 = e0;
    if (v0) e0 = *(const float4*)&ent_bias[nb0];
    if (v1) e1 = *(const float4*)&ent_bias[nb1];
    float eb[8] = {e0.x, e0.y, e0.z, e0.w, e1.x, e1.y, e1.z, e1.w};
#pragma unroll
    for (int i = 0; i < 8; i++) {
        int m = m0 + ty * 8 + i;   // always < BATCH
        float o[8];
#pragma unroll
        for (int j = 0; j < 8; j++) {
            float v = acc[i][j] + eb[j];
            o[j] = 1.0f / (1.0f + __expf(-v));
        }
        if (v0) *(float4*)&out[(size_t)m * N_ENTS + nb0] = make_float4(o[0], o[1], o[2], o[3]);
        if (v1) *(float4*)&out[(size_t)m * N_ENTS + nb1] = make_float4(o[4], o[5], o[6], o[7]);
    }
}

// ================= host launch =================
extern "C" void kernel_launch(void* const* d_in, const int* in_sizes, int n_in,
                              void* d_out, int out_size, void* d_ws, size_t ws_size,
                              hipStream_t stream) {
    const int*   sub        = (const int*)d_in[0];
    const int*   rel        = (const int*)d_in[1];
    const int*   edge_index = (const int*)d_in[2];
    const int*   edge_type  = (const int*)d_in[3];
    const float* init_embed = (const float*)d_in[4];
    const float* init_rel   = (const float*)d_in[5];
    const float* w_in1      = (const float*)d_in[6];
    const float* w_out1     = (const float*)d_in[7];
    const float* w_loop1    = (const float*)d_in[8];
    const float* w_rel1     = (const float*)d_in[9];
    const float* loop_rel1  = (const float*)d_in[10];
    const float* bn_g1      = (const float*)d_in[11];
    const float* bn_b1      = (const float*)d_in[12];
    const float* w_in2      = (const float*)d_in[13];
    const float* w_out2     = (const float*)d_in[14];
    const float* w_loop2    = (const float*)d_in[15];
    const float* w_rel2     = (const float*)d_in[16];
    const float* loop_rel2  = (const float*)d_in[17];
    const float* bn_g2      = (const float*)d_in[18];
    const float* bn_b2      = (const float*)d_in[19];
    const float* conv_w     = (const float*)d_in[20];
    const float* bn0_g      = (const float*)d_in[21];
    const float* bn0_b      = (const float*)d_in[22];
    const float* bn1_g      = (const float*)d_in[23];
    const float* bn1_b      = (const float*)d_in[24];
    const float* bn2_g      = (const float*)d_in[25];
    const float* bn2_b      = (const float*)d_in[26];
    const float* fc_w       = (const float*)d_in[27];
    const float* fc_b       = (const float*)d_in[28];
    const float* ent_bias   = (const float*)d_in[29];

    float* ws = (float*)d_ws;
    float* x1       = ws + WS_X1;
    float* x2       = ws + WS_X2;
    float* r1       = ws + WS_R1;
    float* r2       = ws + WS_R2;
    float* dinv_in  = ws + WS_DINV_IN;
    float* dinv_out = ws + WS_DINV_OUT;
    float* stats    = ws + WS_STATS;
    float* imgraw   = ws + WS_IMGRAW;
    float* fc_acc   = ws + WS_FCACC;
    float* hfin     = ws + WS_HFIN;
    float* big      = ws + WS_BIG;   // layer1: agg1[0,10M) xh1[10M,20M); layer2: agg2[0,20M) xh1[20M,30M); conv_raw[0,20.07M)
    float* out      = (float*)d_out;

    // CSR sort scratch lives in the x2 region (free until gemm_layer<200> writes x2)
    int*  cnt    = (int*)x2;                       // NKEY
    int*  startp = cnt + NKEY;                     // NKEY+1
    int4* rec    = (int4*)(cnt + 2 * NKEY + 8);    // E_TOT records, 16B-aligned

    // zero accumulators (ws is poisoned 0xAA before every call)
    hipMemsetAsync(stats, 0, 4096 * sizeof(float), stream);
    hipMemsetAsync(fc_acc, 0, BATCH * DD * sizeof(float), stream);
    hipMemsetAsync(cnt, 0, NKEY * sizeof(int), stream);

    // CSR build (once; reused by both layers). degrees come from the histogram.
    hist_kernel<<<(E_TOT + 255) / 256, 256, 0, stream>>>(edge_index, cnt);
    dinv_kernel<<<(N_ENTS + 255) / 256, 256, 0, stream>>>(cnt, dinv_in, dinv_out);
    scan_kernel<<<1, 1024, 0, stream>>>(cnt, startp);
    fill_kernel<<<(E_TOT + 255) / 256, 256, 0, stream>>>(edge_index, edge_type,
                                                         dinv_in, dinv_out, startp, rec);

    // ---- layer 1 ----  (agg stride 200 = in|out halves; loop fused; split-K z=2)
    seg_kernel<100, 200><<<NKEY, 128, 0, stream>>>(startp, cnt, rec, init_embed, init_rel, big);
    {
        dim3 g((N_ENTS + 127) / 128, (DD + 127) / 128, 2);
        gemm_layer<100><<<g, 256, 0, stream>>>(big, init_embed, loop_rel1,
                                               w_in1, w_out1, w_loop1, dinv_in, dinv_out,
                                               x1, big + 10000000);
    }
    feat_stats_kernel<<<256, 256, 0, stream>>>(x1, big + 10000000, N_ENTS,
                                               stats + ST_L1_SUM, stats + ST_L1_SQ);
    layer_apply_kernel<<<(N_ENTS * DD + 255) / 256, 256, 0, stream>>>(x1, big + 10000000,
                                                                      stats + ST_L1_SUM,
                                                                      stats + ST_L1_SQ, bn_g1, bn_b1);
    rel_kernel<100><<<N_RELS, 256, 0, stream>>>(init_rel, w_rel1, r1);

    // ---- layer 2 ----  (agg stride 400; split-K z=2)
    seg_kernel<200, 400><<<NKEY, 256, 0, stream>>>(startp, cnt, rec, x1, r1, big);
    {
        dim3 g((N_ENTS + 127) / 128, (DD + 127) / 128, 2);
        gemm_layer<200><<<g, 256, 0, stream>>>(big, x1, loop_rel2,
                                               w_in2, w_out2, w_loop2, dinv_in, dinv_out,
                                               x2, big + 20000000);
    }
    feat_stats_kernel<<<256, 256, 0, stream>>>(x2, big + 20000000, N_ENTS,
                                               stats + ST_L2_SUM, stats + ST_L2_SQ);
    layer_apply_kernel<<<(N_ENTS * DD + 255) / 256, 256, 0, stream>>>(x2, big + 20000000,
                                                                      stats + ST_L2_SUM,
                                                                      stats + ST_L2_SQ, bn_g2, bn_b2);
    rel_kernel<200><<<N_RELS, 256, 0, stream>>>(r1, w_rel2, r2);

    // ---- ConvE scorer ----
    gather_kernel<<<BATCH, 512, 0, stream>>>(sub, rel, x2, r2, imgraw, stats + ST_BN0);
    {
        dim3 g(BATCH, 4);   // 4-way filter split
        conv_kernel<<<g, 256, 0, stream>>>(imgraw, stats + ST_BN0, bn0_g, bn0_b, conv_w, big);
    }
    bn1_stats_kernel<<<BATCH * NFILT, 64, 0, stream>>>(big, stats + ST_BN1_SUM, stats + ST_BN1_SQ);
    bn1_coef_kernel<<<1, 256, 0, stream>>>(stats + ST_BN1_SUM, stats + ST_BN1_SQ, bn1_g, bn1_b,
                                           stats + ST_S1, stats + ST_T1);
    {
        dim3 g(BATCH / 64, 49);   // split-K: 49 chunks of 800
        gemm_fc<<<g, 256, 0, stream>>>(big, fc_w, stats + ST_S1, stats + ST_T1, fc_acc);
    }
    bn2_stats_kernel<<<NFILT, 64, 0, stream>>>(fc_acc, fc_b, stats + ST_BN2_SUM, stats + ST_BN2_SQ);
    hfin_kernel<<<(BATCH * DD + 255) / 256, 256, 0, stream>>>(fc_acc, fc_b, stats + ST_BN2_SUM,
                                                              stats + ST_BN2_SQ, bn2_g, bn2_b, hfin);
    {
        dim3 g(BATCH / 128, (N_ENTS + 127) / 128);
        gemm_logits<<<g, 256, 0, stream>>>(hfin, x2, ent_bias, out);
    }
}